// Round 7
// baseline (739.041 us; speedup 1.0000x reference)
//
#include <hip/hip_runtime.h>
#include <hip/hip_bf16.h>

// Sizes (fixed by the reference)
//  V=32000, T=48, E=128, HID=256, H=128, B=256, L=512, 4H=512
typedef unsigned short ushort_t;
typedef unsigned int uint_t;
typedef __bf16 bf16x8 __attribute__((ext_vector_type(8)));
typedef float f32x4 __attribute__((ext_vector_type(4)));
typedef float f32x16 __attribute__((ext_vector_type(16)));

#define L2E 1.44269504088896340736f
#define LN2 0.69314718055994530942f

// LDS-only barrier: does NOT drain vmcnt -> global loads/stores stay in flight.
#define WGBAR() __asm__ volatile("s_waitcnt lgkmcnt(0)\n\ts_barrier" ::: "memory")
// In-wave LDS RAW fence for single-wave workgroups.
#define LGKM0() __asm__ volatile("s_waitcnt lgkmcnt(0)" ::: "memory")

static __device__ __forceinline__ float fexp2(float x) { return __builtin_amdgcn_exp2f(x); }
static __device__ __forceinline__ float flog2(float x) { return __builtin_amdgcn_logf(x); }
static __device__ __forceinline__ float frcp (float x) { return __builtin_amdgcn_rcpf(x); }

static __device__ __forceinline__ float sigm(float x) {
  return frcp(1.0f + fexp2(-L2E * x));
}
static __device__ __forceinline__ float tanha(float x) {
  return 1.0f - 2.0f * frcp(1.0f + fexp2(2.0f * L2E * x));
}

static __device__ __forceinline__ ushort_t f2bf(float f) {
  union { float f; uint_t u; } v; v.f = f;
  uint_t u = v.u;
  uint_t r = (u + 0x7fffu + ((u >> 16) & 1u)) >> 16;  // RNE
  return (ushort_t)r;
}
static __device__ __forceinline__ bf16x8 pack8(float4 a, float4 b) {
  uint4 u = make_uint4(
      (uint_t)f2bf(a.x) | ((uint_t)f2bf(a.y) << 16),
      (uint_t)f2bf(a.z) | ((uint_t)f2bf(a.w) << 16),
      (uint_t)f2bf(b.x) | ((uint_t)f2bf(b.y) << 16),
      (uint_t)f2bf(b.z) | ((uint_t)f2bf(b.w) << 16));
  return __builtin_bit_cast(bf16x8, u);
}
static __device__ __forceinline__ bf16x8 zero8() {
  uint4 z = make_uint4(0u, 0u, 0u, 0u);
  return __builtin_bit_cast(bf16x8, z);
}
static __device__ __forceinline__ uint2 pack4(float4 a) {
  return make_uint2((uint_t)f2bf(a.x) | ((uint_t)f2bf(a.y) << 16),
                    (uint_t)f2bf(a.z) | ((uint_t)f2bf(a.w) << 16));
}

// ---------------------------------------------------------------------------
// K2 v6 (unchanged from R6; math identical to the R5-passing v5): fully-fused
// BiLSTM. grid = 256 WGs x 512 thr; wg>>7 = dir, (wg&127)*2 = 2 batch rows.
// Recurrence K=128 (16 MFMA/wave/step); xp = emb[words]@Wih^T + bias produced
// in-kernel in dense 8-step blocks. Quad-0 lanes own both rows' gates in
// C-regs [0],[1] and run both rows' activations. Raw lgkm barrier per step.
// ---------------------------------------------------------------------------
__global__ __launch_bounds__(512, 2) void k2_lstm(
    const int* __restrict__ words, const float* __restrict__ emb,
    const float* __restrict__ Wih_f, const float* __restrict__ Whh_f,
    const float* __restrict__ bih_f, const float* __restrict__ bhh_f,
    const float* __restrict__ Wih_b, const float* __restrict__ Whh_b,
    const float* __restrict__ bih_b, const float* __restrict__ bhh_b,
    ushort_t* __restrict__ h_f, ushort_t* __restrict__ h_b) {
  const int wg = blockIdx.x;
  const int dir = wg >> 7;
  const int r0 = (wg & 127) << 1;
  const float* Whh = dir ? Whh_b : Whh_f;
  const float* Wih = dir ? Wih_b : Wih_f;
  const float* bih = dir ? bih_b : bih_f;
  const float* bhh = dir ? bhh_b : bhh_f;
  ushort_t* hout = dir ? h_b : h_f;

  const int tid = threadIdx.x;
  const int w = tid >> 6;        // wave 0..7
  const int lane = tid & 63;
  const int l15 = lane & 15;
  const int kq = lane >> 4;      // 0..3

  __shared__ __align__(16) ushort_t hx[2][2][136];      //  1,088 B
  __shared__ __align__(16) ushort_t xp[2][16][128][4];  // 32,768 B
  __shared__ __align__(16) ushort_t xs[2][16][136];     //  8,704 B

  // ---- register-resident weight fragments (bf16), [quadrant][K-chunk] ----
  // B layout (16x16x32): col n = lane&15, k = (lane>>4)*8 + j
  bf16x8 wfh[4][4], wfx[4][4];
  float biasP[4];   // production bias for col w*16+l15, quadrant Q
#pragma unroll
  for (int Q = 0; Q < 4; ++Q) {
    const int n = Q * 128 + w * 16 + l15;
    biasP[Q] = bih[n] + bhh[n];
#pragma unroll
    for (int c = 0; c < 4; ++c) {
      const int k0 = c * 32 + kq * 8;
      const float* sh = Whh + n * 128 + k0;
      const float* sx = Wih + n * 128 + k0;
      wfh[Q][c] = pack8(*(const float4*)sh, *(const float4*)(sh + 4));
      wfx[Q][c] = pack8(*(const float4*)sx, *(const float4*)(sx + 4));
    }
  }

  const int uj = w * 16 + l15;
  float cst0 = 0.f, cst1 = 0.f;

  // staging thread mapping: 512 thr cover 16 rows x 128 cols (4 floats each)
  const int sm = tid >> 5;          // xs row 0..15  (tl = sm>>1, r = sm&1)
  const int sc = (tid & 31) * 4;    // col 0..124
  const int str = r0 + (sm & 1);
  const int stl = sm >> 1;

  // ---- prologue ----
  if (tid < 256) hx[0][tid >> 7][tid & 127] = 0;   // h(-1) = 0
  {  // stage xs[1] = x(block 0)
    const int tg = stl;
    const int tf = dir ? (511 - tg) : tg;
    const int word = words[str * 512 + tf];
    float4 av = *(const float4*)(emb + (size_t)word * 128 + sc);
    *(uint2*)&xs[1][sm][sc] = pack4(av);
  }
  WGBAR();
  // produce xp[0] from xs[1] (16 dense MFMAs/wave), bias in C-init
#pragma unroll
  for (int Q = 0; Q < 4; ++Q) {
    f32x4 pc = {biasP[Q], biasP[Q], biasP[Q], biasP[Q]};
#pragma unroll
    for (int c = 0; c < 4; ++c) {
      bf16x8 af = __builtin_bit_cast(bf16x8, *(const uint4*)&xs[1][l15][kq * 8 + c * 32]);
      pc = __builtin_amdgcn_mfma_f32_16x16x32_bf16(af, wfx[Q][c], pc, 0, 0, 0);
    }
#pragma unroll
    for (int rr = 0; rr < 4; ++rr)
      xp[0][kq * 4 + rr][w * 16 + l15][Q] = f2bf(pc[rr]);
  }
  {  // stage xs[0] = x(block 1)
    const int tg = 8 + stl;
    const int tf = dir ? (511 - tg) : tg;
    const int word = words[str * 512 + tf];
    float4 av = *(const float4*)(emb + (size_t)word * 128 + sc);
    *(uint2*)&xs[0][sm][sc] = pack4(av);
  }
  WGBAR();

  int sword = 0;
  float4 se0 = make_float4(0.f, 0.f, 0.f, 0.f);

#pragma unroll 1
  for (int i = 0; i < 64; ++i) {   // 64 blocks of 8 steps
    const int pcon = i & 1;        // consume xp[pcon]; production reads xs[pcon]
    const int ppro = pcon ^ 1;     // produce xp[ppro]; staging writes xs[ppro]
    f32x4 pc = {0.f, 0.f, 0.f, 0.f};
#pragma unroll
    for (int s = 0; s < 8; ++s) {
      const int t = i * 8 + s;
      const int p = t & 1;
      // xp consumption: both rows (b64 each, wave-broadcast reads)
      const uint2 xqA = *(const uint2*)&xp[pcon][2 * s + 0][uj][0];
      const uint2 xqB = *(const uint2*)&xp[pcon][2 * s + 1][uj][0];
      // staging pipeline for x(block i+2): word @s0, emb @s2, LDS write @s6
      if (i < 62) {
        if (s == 0) {
          const int tg = (i + 2) * 8 + stl;
          const int tf = dir ? (511 - tg) : tg;
          sword = words[str * 512 + tf];
        }
        if (s == 2) se0 = *(const float4*)(emb + (size_t)sword * 128 + sc);
        if (s == 6) *(uint2*)&xs[ppro][sm][sc] = pack4(se0);
      }
      // ---- recurrence MFMAs: gates_h = h @ Whh^T (K=128) ----
      f32x4 a0 = {0.f, 0.f, 0.f, 0.f}, a1 = a0, a2 = a0, a3 = a0;
      const ushort_t* abase = &hx[p][l15 & 1][kq * 8];
#pragma unroll
      for (int c = 0; c < 4; ++c) {
        bf16x8 af = __builtin_bit_cast(bf16x8, *(const uint4*)(abase + c * 32));
        a0 = __builtin_amdgcn_mfma_f32_16x16x32_bf16(af, wfh[0][c], a0, 0, 0, 0);
        a1 = __builtin_amdgcn_mfma_f32_16x16x32_bf16(af, wfh[1][c], a1, 0, 0, 0);
        a2 = __builtin_amdgcn_mfma_f32_16x16x32_bf16(af, wfh[2][c], a2, 0, 0, 0);
        a3 = __builtin_amdgcn_mfma_f32_16x16x32_bf16(af, wfh[3][c], a3, 0, 0, 0);
      }
      // ---- production MFMAs for block i+1 (independent; fills bubbles) ----
      if (i < 63) {
        const int Q = s >> 1;
        if ((s & 1) == 0) {
          pc = f32x4{biasP[Q], biasP[Q], biasP[Q], biasP[Q]};
          bf16x8 af0 = __builtin_bit_cast(bf16x8, *(const uint4*)&xs[pcon][l15][kq * 8]);
          bf16x8 af1 = __builtin_bit_cast(bf16x8, *(const uint4*)&xs[pcon][l15][kq * 8 + 32]);
          pc = __builtin_amdgcn_mfma_f32_16x16x32_bf16(af0, wfx[Q][0], pc, 0, 0, 0);
          pc = __builtin_amdgcn_mfma_f32_16x16x32_bf16(af1, wfx[Q][1], pc, 0, 0, 0);
        } else {
          bf16x8 af2 = __builtin_bit_cast(bf16x8, *(const uint4*)&xs[pcon][l15][kq * 8 + 64]);
          bf16x8 af3 = __builtin_bit_cast(bf16x8, *(const uint4*)&xs[pcon][l15][kq * 8 + 96]);
          pc = __builtin_amdgcn_mfma_f32_16x16x32_bf16(af2, wfx[Q][2], pc, 0, 0, 0);
          pc = __builtin_amdgcn_mfma_f32_16x16x32_bf16(af3, wfx[Q][3], pc, 0, 0, 0);
#pragma unroll
          for (int rr = 0; rr < 4; ++rr)
            xp[ppro][kq * 4 + rr][w * 16 + l15][Q] = f2bf(pc[rr]);
        }
      }
      // ---- act: quad-0 lanes own rows 0,1 in C-regs [0],[1]; no shuffles ----
      if (lane < 16) {
        // row 0
        float g0 = a0[0] + __builtin_bit_cast(float, xqA.x << 16);
        float g1 = a1[0] + __builtin_bit_cast(float, xqA.x & 0xffff0000u);
        float g2 = a2[0] + __builtin_bit_cast(float, xqA.y << 16);
        float g3 = a3[0] + __builtin_bit_cast(float, xqA.y & 0xffff0000u);
        float si = sigm(g0), sf = sigm(g1), so = sigm(g3);
        float tg = tanha(g2);
        cst0 = sf * cst0 + si * tg;
        const ushort_t hb0 = f2bf(so * tanha(cst0));
        // row 1
        float G0 = a0[1] + __builtin_bit_cast(float, xqB.x << 16);
        float G1 = a1[1] + __builtin_bit_cast(float, xqB.x & 0xffff0000u);
        float G2 = a2[1] + __builtin_bit_cast(float, xqB.y << 16);
        float G3 = a3[1] + __builtin_bit_cast(float, xqB.y & 0xffff0000u);
        float Si = sigm(G0), Sf = sigm(G1), So = sigm(G3);
        float Tg = tanha(G2);
        cst1 = Sf * cst1 + Si * Tg;
        const ushort_t hb1 = f2bf(So * tanha(cst1));
        hx[p ^ 1][0][uj] = hb0;
        hx[p ^ 1][1][uj] = hb1;
        const int tf = dir ? (511 - t) : t;
        hout[(tf * 256 + r0) * 128 + uj] = hb0;        // stays in flight
        hout[(tf * 256 + r0 + 1) * 128 + uj] = hb1;
      }
      WGBAR();
    }
  }
}

// ---------------------------------------------------------------------------
// K3: emis[t*256+b][48] = [h_f|h_b] @ Wout^T + bout  (fp32 out)
// ---------------------------------------------------------------------------
__global__ __launch_bounds__(256, 2) void k3_emis(
    const ushort_t* __restrict__ h_f, const ushort_t* __restrict__ h_b,
    const float* __restrict__ Wout, const float* __restrict__ bout,
    float* __restrict__ emis) {
  const int w = threadIdx.x >> 6;
  const int lane = threadIdx.x & 63;
  const int m31 = lane & 31;
  const int q = lane >> 5;
  const int Mbase = blockIdx.x * 128 + w * 32;

  bf16x8 bfr[2][16];
  float bo[2];
#pragma unroll
  for (int T = 0; T < 2; ++T) {
    const int n = T * 32 + m31;
    if (n < 48) {
      bo[T] = bout[n];
#pragma unroll
      for (int c = 0; c < 16; ++c) {
        const float* src = Wout + n * 256 + c * 16 + q * 8;
        bfr[T][c] = pack8(*(const float4*)src, *(const float4*)(src + 4));
      }
    } else {
      bo[T] = 0.f;
#pragma unroll
      for (int c = 0; c < 16; ++c) bfr[T][c] = zero8();
    }
  }
  f32x16 acc0{}, acc1{};
  const ushort_t* hrf = h_f + (long)(Mbase + m31) * 128;
  const ushort_t* hrb = h_b + (long)(Mbase + m31) * 128;
#pragma unroll
  for (int c = 0; c < 16; ++c) {
    const ushort_t* src = (c < 8) ? (hrf + c * 16 + q * 8) : (hrb + (c - 8) * 16 + q * 8);
    bf16x8 af = __builtin_bit_cast(bf16x8, *(const uint4*)src);
    acc0 = __builtin_amdgcn_mfma_f32_32x32x16_bf16(af, bfr[0][c], acc0, 0, 0, 0);
    acc1 = __builtin_amdgcn_mfma_f32_32x32x16_bf16(af, bfr[1][c], acc1, 0, 0, 0);
  }
#pragma unroll
  for (int T = 0; T < 2; ++T) {
    const int n = T * 32 + m31;
    if (n >= 48) continue;
    f32x16 A = T ? acc1 : acc0;
#pragma unroll
    for (int r = 0; r < 16; ++r) {
      const int row = (r & 3) + ((r >> 2) << 3) + (q << 2);
      emis[(long)(Mbase + row) * 48 + n] = A[r] + bo[T];
    }
  }
}

// ---------------------------------------------------------------------------
// K4 v6: CRF forward, 16 chains per wave via MFMA, LDS-based C->B transform.
//   D[16 chains][48] as B-operand (col = chain), P^T tiles as static A-frags
//   (A[m = j][k = i] = P[i][j], bf16, regs). Per step:
//     C = P^T x D (6 MFMAs)  ->  D' = msk ? C * 2^{em*L2E - e} : D
//     pack D' to bf16 -> d16[chain][j] (3 ds_write_b64) -> lgkm fence ->
//     re-read B-frags (2 ds_read_b128) + e from d16[chain][0] bits.
//   Int S accumulates e per masked step (exact bookkeeping).
// grid = 16 WGs x 64 thr (one wave per WG; no barriers, lgkm fences only).
// ---------------------------------------------------------------------------
__global__ __launch_bounds__(64) void k4_den(
    const int* __restrict__ words, const float* __restrict__ emis,
    const float* __restrict__ trans, const float* __restrict__ st,
    const float* __restrict__ et, float* __restrict__ denom) {
  const int lane = threadIdx.x;
  const int r = lane & 15;       // chain within WG (C/B column)
  const int kq = lane >> 4;      // quad
  const int b = blockIdx.x * 16 + r;

  __shared__ __align__(16) ushort_t d16[16][72];   // [chain][tag j], 2,304 B

  // ---- A-frags: PA[mt][c]; A[m = mt*16 + l15][k-elem e] = P[i][j],
  //      i = c*32 + kq*8 + e, j = mt*16 + l15 ----
  bf16x8 PA[3][2];
#pragma unroll
  for (int mt = 0; mt < 3; ++mt)
#pragma unroll
    for (int c = 0; c < 2; ++c) {
      const int j = mt * 16 + r;
      uint_t qv[4];
#pragma unroll
      for (int p = 0; p < 4; ++p) {
        const int i0 = c * 32 + kq * 8 + 2 * p;
        const float v0 = (i0 < 48) ? fexp2(trans[i0 * 48 + j] * L2E) : 0.f;
        const float v1 = (i0 + 1 < 48) ? fexp2(trans[(i0 + 1) * 48 + j] * L2E) : 0.f;
        qv[p] = (uint_t)f2bf(v0) | ((uint_t)f2bf(v1) << 16);
      }
      PA[mt][c] = __builtin_bit_cast(bf16x8, make_uint4(qv[0], qv[1], qv[2], qv[3]));
    }

  // ---- state init: dold (C-layout fp32), then d16, then B-frags ----
  float4 dold[3];
#pragma unroll
  for (int mt = 0; mt < 3; ++mt)
#pragma unroll
    for (int rr = 0; rr < 4; ++rr) {
      const int j = mt * 16 + kq * 4 + rr;
      (&dold[mt].x)[rr] = fexp2((st[j] + emis[b * 48 + j]) * L2E);
    }
#pragma unroll
  for (int mt = 0; mt < 3; ++mt) {
    uint2 pk = make_uint2(
        (uint_t)f2bf(dold[mt].x) | ((uint_t)f2bf(dold[mt].y) << 16),
        (uint_t)f2bf(dold[mt].z) | ((uint_t)f2bf(dold[mt].w) << 16));
    *(uint2*)&d16[r][mt * 16 + kq * 4] = pk;
  }
  LGKM0();
  bf16x8 bd[2];
  bd[0] = __builtin_bit_cast(bf16x8, *(const uint4*)&d16[r][kq * 8]);
  {
    uint4 u1 = *(const uint4*)&d16[r][32 + (kq & 1) * 8];
    if (kq >= 2) u1 = make_uint4(0u, 0u, 0u, 0u);
    bd[1] = __builtin_bit_cast(bf16x8, u1);
  }
  int e_pend = (int)((d16[r][0] >> 7) & 0xffu) - 127;
  float e_pf = (float)e_pend;
  int S = 0;

  // em/words prefetch (depth 2)
  float4 emA[3], emB[3];
#pragma unroll
  for (int mt = 0; mt < 3; ++mt) {
    emA[mt] = *(const float4*)&emis[(1 * 256 + b) * 48 + mt * 16 + kq * 4];
    emB[mt] = *(const float4*)&emis[(2 * 256 + b) * 48 + mt * 16 + kq * 4];
  }
  int wvA = words[b * 512 + 1];
  int wvB = words[b * 512 + 2];

#pragma unroll 1
  for (int t = 1; t < 512; ++t) {
    // E = 2^(em*L2E - e_pend); renorm folded, off the MFMA chain
    float4 EF[3];
#pragma unroll
    for (int mt = 0; mt < 3; ++mt)
#pragma unroll
      for (int rr = 0; rr < 4; ++rr)
        (&EF[mt].x)[rr] = fexp2(fmaf((&emA[mt].x)[rr], L2E, -e_pf));
    const bool msk = (wvA != 0);
    // rotate prefetch, issue t+2 loads (stay in flight)
    const int tn = min(511, t + 2);
#pragma unroll
    for (int mt = 0; mt < 3; ++mt) emA[mt] = emB[mt];
#pragma unroll
    for (int mt = 0; mt < 3; ++mt)
      emB[mt] = *(const float4*)&emis[(tn * 256 + b) * 48 + mt * 16 + kq * 4];
    wvA = wvB; wvB = words[b * 512 + tn];

    // ---- 6 MFMAs: C[m=j][n=chain] over 3 m-tiles x 2 K-chunks ----
    f32x4 C0{}, C1{}, C2{};
    C0 = __builtin_amdgcn_mfma_f32_16x16x32_bf16(PA[0][0], bd[0], C0, 0, 0, 0);
    C1 = __builtin_amdgcn_mfma_f32_16x16x32_bf16(PA[1][0], bd[0], C1, 0, 0, 0);
    C2 = __builtin_amdgcn_mfma_f32_16x16x32_bf16(PA[2][0], bd[0], C2, 0, 0, 0);
    C0 = __builtin_amdgcn_mfma_f32_16x16x32_bf16(PA[0][1], bd[1], C0, 0, 0, 0);
    C1 = __builtin_amdgcn_mfma_f32_16x16x32_bf16(PA[1][1], bd[1], C1, 0, 0, 0);
    C2 = __builtin_amdgcn_mfma_f32_16x16x32_bf16(PA[2][1], bd[1], C2, 0, 0, 0);

    // ---- scale by E, masked select (chain = lane col; msk per lane) ----
#pragma unroll
    for (int rr = 0; rr < 4; ++rr) {
      (&dold[0].x)[rr] = msk ? C0[rr] * (&EF[0].x)[rr] : (&dold[0].x)[rr];
      (&dold[1].x)[rr] = msk ? C1[rr] * (&EF[1].x)[rr] : (&dold[1].x)[rr];
      (&dold[2].x)[rr] = msk ? C2[rr] * (&EF[2].x)[rr] : (&dold[2].x)[rr];
    }
    if (msk) S += e_pend;

    // ---- pack new D to bf16, round-trip through LDS to B-layout ----
#pragma unroll
    for (int mt = 0; mt < 3; ++mt) {
      uint2 pk = make_uint2(
          (uint_t)f2bf(dold[mt].x) | ((uint_t)f2bf(dold[mt].y) << 16),
          (uint_t)f2bf(dold[mt].z) | ((uint_t)f2bf(dold[mt].w) << 16));
      *(uint2*)&d16[r][mt * 16 + kq * 4] = pk;
    }
    LGKM0();
    bd[0] = __builtin_bit_cast(bf16x8, *(const uint4*)&d16[r][kq * 8]);
    {
      uint4 u1 = *(const uint4*)&d16[r][32 + (kq & 1) * 8];
      if (kq >= 2) u1 = make_uint4(0u, 0u, 0u, 0u);
      bd[1] = __builtin_bit_cast(bf16x8, u1);
    }
    e_pend = (int)((d16[r][0] >> 7) & 0xffu) - 127;
    e_pf = (float)e_pend;
  }

  // ---- epilogue: denom = (S + log2(sum_j D[j]*2^{et_j*L2E})) * ln2 ----
  float psum = 0.f;
#pragma unroll
  for (int mt = 0; mt < 3; ++mt)
#pragma unroll
    for (int rr = 0; rr < 4; ++rr) {
      const int j = mt * 16 + kq * 4 + rr;
      psum += (&dold[mt].x)[rr] * fexp2(et[j] * L2E);
    }
  psum += __shfl_xor(psum, 16, 64);
  psum += __shfl_xor(psum, 32, 64);
  if (lane < 16) denom[b] = ((float)S + flog2(psum)) * LN2;
}

// ---------------------------------------------------------------------------
// K4b: CRF numerator (gold path score).
// ---------------------------------------------------------------------------
__global__ void k4b_num(const int* __restrict__ words, const int* __restrict__ tags,
                        const float* __restrict__ emis, const float* __restrict__ trans,
                        const float* __restrict__ st, const float* __restrict__ et,
                        float* __restrict__ num) {
  const int b = blockIdx.x;
  const int lane = threadIdx.x;
  float s = 0.f;
  int cnt = 0;
#pragma unroll 1
  for (int s8 = 0; s8 < 8; ++s8) {
    const int t = lane + (s8 << 6);
    const int wv = words[b * 512 + t];
    const int tg = tags[b * 512 + t];
    const bool mt = (wv != 0);
    cnt += mt ? 1 : 0;
    if (t == 0) {
      s += st[tg] + emis[b * 48 + tg];
    } else if (mt) {
      const int tp = tags[b * 512 + t - 1];
      s += trans[tp * 48 + tg] + emis[(t * 256 + b) * 48 + tg];
    }
  }
#pragma unroll
  for (int d = 32; d; d >>= 1) {
    s += __shfl_xor(s, d, 64);
    cnt += __shfl_xor(cnt, d, 64);
  }
  if (lane == 0) {
    const int lt = tags[b * 512 + cnt - 1];
    num[b] = s + et[lt];
  }
}

// ---------------------------------------------------------------------------
// K5: loss = -mean(num - denom)
// ---------------------------------------------------------------------------
__global__ void k5_loss(const float* __restrict__ num, const float* __restrict__ denom,
                        float* __restrict__ out) {
  const int tid = threadIdx.x;
  float v = num[tid] - denom[tid];
#pragma unroll
  for (int d = 32; d; d >>= 1) v += __shfl_xor(v, d, 64);
  __shared__ float p[4];
  if ((tid & 63) == 0) p[tid >> 6] = v;
  __syncthreads();
  if (tid == 0) out[0] = -(p[0] + p[1] + p[2] + p[3]) * (1.0f / 256.0f);
}

// ---------------------------------------------------------------------------
extern "C" void kernel_launch(void* const* d_in, const int* in_sizes, int n_in,
                              void* d_out, int out_size, void* d_ws, size_t ws_size,
                              hipStream_t stream) {
  (void)in_sizes; (void)n_in; (void)out_size; (void)ws_size;
  const int*   words = (const int*)d_in[0];
  const int*   tags  = (const int*)d_in[1];
  // d_in[2] = mask (bool) -- unused; reconstructed as words != 0
  const float* emb   = (const float*)d_in[3];
  const float* Wih_f = (const float*)d_in[4];
  const float* Whh_f = (const float*)d_in[5];
  const float* bih_f = (const float*)d_in[6];
  const float* bhh_f = (const float*)d_in[7];
  const float* Wih_b = (const float*)d_in[8];
  const float* Whh_b = (const float*)d_in[9];
  const float* bih_b = (const float*)d_in[10];
  const float* bhh_b = (const float*)d_in[11];
  const float* Wout  = (const float*)d_in[12];
  const float* bout  = (const float*)d_in[13];
  const float* trans = (const float*)d_in[14];
  const float* st    = (const float*)d_in[15];
  const float* et    = (const float*)d_in[16];

  char* ws = (char*)d_ws;
  ushort_t* h_f   = (ushort_t*)(ws);                    // 33,554,432 B
  ushort_t* h_b   = (ushort_t*)(ws + 33554432);         // 33,554,432 B
  float*    emis  = (float*)   (ws + 67108864);         // 25,165,824 B
  float*    denom = (float*)   (ws + 92274688);         //      1,024 B
  float*    num   = (float*)   (ws + 92275712);         //      1,024 B
  // total ws needed: ~92.3 MB (within the known-good 125.8 MB envelope)

  k2_lstm <<<256, 512, 0, stream>>>(words, emb,
                                    Wih_f, Whh_f, bih_f, bhh_f,
                                    Wih_b, Whh_b, bih_b, bhh_b,
                                    h_f, h_b);
  k3_emis <<<1024, 256, 0, stream>>>(h_f, h_b, Wout, bout, emis);
  k4_den  <<<16, 64, 0, stream>>>(words, emis, trans, st, et, denom);
  k4b_num <<<256, 64, 0, stream>>>(words, tags, emis, trans, st, et, num);
  k5_loss <<<1, 256, 0, stream>>>(num, denom, (float*)d_out);
}

// Round 8
// 715.407 us; speedup vs baseline: 1.0330x; 1.0330x over previous
//
#include <hip/hip_runtime.h>
#include <hip/hip_bf16.h>

// Sizes (fixed by the reference)
//  V=32000, T=48, E=128, HID=256, H=128, B=256, L=512, 4H=512
typedef unsigned short ushort_t;
typedef unsigned int uint_t;
typedef __bf16 bf16x8 __attribute__((ext_vector_type(8)));
typedef float f32x4 __attribute__((ext_vector_type(4)));
typedef float f32x16 __attribute__((ext_vector_type(16)));

#define L2E 1.44269504088896340736f
#define LN2 0.69314718055994530942f

// LDS-only barrier: does NOT drain vmcnt -> global loads/stores stay in flight.
#define WGBAR() __asm__ volatile("s_waitcnt lgkmcnt(0)\n\ts_barrier" ::: "memory")

static __device__ __forceinline__ float fexp2(float x) { return __builtin_amdgcn_exp2f(x); }
static __device__ __forceinline__ float flog2(float x) { return __builtin_amdgcn_logf(x); }
static __device__ __forceinline__ float frcp (float x) { return __builtin_amdgcn_rcpf(x); }

static __device__ __forceinline__ float sigm(float x) {
  return frcp(1.0f + fexp2(-L2E * x));
}
static __device__ __forceinline__ float tanha(float x) {
  return 1.0f - 2.0f * frcp(1.0f + fexp2(2.0f * L2E * x));
}

static __device__ __forceinline__ ushort_t f2bf(float f) {
  union { float f; uint_t u; } v; v.f = f;
  uint_t u = v.u;
  uint_t r = (u + 0x7fffu + ((u >> 16) & 1u)) >> 16;  // RNE
  return (ushort_t)r;
}
static __device__ __forceinline__ bf16x8 pack8(float4 a, float4 b) {
  uint4 u = make_uint4(
      (uint_t)f2bf(a.x) | ((uint_t)f2bf(a.y) << 16),
      (uint_t)f2bf(a.z) | ((uint_t)f2bf(a.w) << 16),
      (uint_t)f2bf(b.x) | ((uint_t)f2bf(b.y) << 16),
      (uint_t)f2bf(b.z) | ((uint_t)f2bf(b.w) << 16));
  return __builtin_bit_cast(bf16x8, u);
}
static __device__ __forceinline__ bf16x8 zero8() {
  uint4 z = make_uint4(0u, 0u, 0u, 0u);
  return __builtin_bit_cast(bf16x8, z);
}
static __device__ __forceinline__ uint2 pack4(float4 a) {
  return make_uint2((uint_t)f2bf(a.x) | ((uint_t)f2bf(a.y) << 16),
                    (uint_t)f2bf(a.z) | ((uint_t)f2bf(a.w) << 16));
}
// bf16 RNE round with exponent renorm: round(v * 2^-e)
static __device__ __forceinline__ uint_t rnbf(float v, int esh) {
  uint_t u = __builtin_bit_cast(uint_t, v) - (uint_t)(esh << 23);
  return (u + 0x7fffu + ((u >> 16) & 1u)) >> 16;
}

// ---------------------------------------------------------------------------
// K2 v5 (revert to R5's measured-best 383 us): fully-fused BiLSTM.
// grid = 256 WGs x 512 thr; wg>>7 = dir, (wg&127)*2 = 2 batch rows.
// Recurrence K=128 (16 MFMA/wave/step); xp = emb[words]@Wih^T + bias produced
// in-kernel in dense 8-step blocks (2 MFMA/wave/step). xp layout [16][128][4]
// (one b64 consumption read); bias folded into production C-init; 4-shuffle
// gate redistribution spreads act over 32 lanes. Raw lgkm barrier per step.
// ---------------------------------------------------------------------------
__global__ __launch_bounds__(512, 2) void k2_lstm(
    const int* __restrict__ words, const float* __restrict__ emb,
    const float* __restrict__ Wih_f, const float* __restrict__ Whh_f,
    const float* __restrict__ bih_f, const float* __restrict__ bhh_f,
    const float* __restrict__ Wih_b, const float* __restrict__ Whh_b,
    const float* __restrict__ bih_b, const float* __restrict__ bhh_b,
    ushort_t* __restrict__ h_f, ushort_t* __restrict__ h_b) {
  const int wg = blockIdx.x;
  const int dir = wg >> 7;
  const int r0 = (wg & 127) << 1;
  const float* Whh = dir ? Whh_b : Whh_f;
  const float* Wih = dir ? Wih_b : Wih_f;
  const float* bih = dir ? bih_b : bih_f;
  const float* bhh = dir ? bhh_b : bhh_f;
  ushort_t* hout = dir ? h_b : h_f;

  const int tid = threadIdx.x;
  const int w = tid >> 6;        // wave 0..7
  const int lane = tid & 63;
  const int l15 = lane & 15;
  const int kq = lane >> 4;      // 0..3

  __shared__ __align__(16) ushort_t hx[2][2][136];      //  1,088 B
  __shared__ __align__(16) ushort_t xp[2][16][128][4];  // 32,768 B
  __shared__ __align__(16) ushort_t xs[2][16][136];     //  8,704 B

  // ---- register-resident weight fragments (bf16), [quadrant][K-chunk] ----
  // B layout (16x16x32): col n = lane&15, k = (lane>>4)*8 + j
  bf16x8 wfh[4][4], wfx[4][4];
  float biasP[4];   // production bias for col w*16+l15, quadrant Q
#pragma unroll
  for (int Q = 0; Q < 4; ++Q) {
    const int n = Q * 128 + w * 16 + l15;
    biasP[Q] = bih[n] + bhh[n];
#pragma unroll
    for (int c = 0; c < 4; ++c) {
      const int k0 = c * 32 + kq * 8;
      const float* sh = Whh + n * 128 + k0;
      const float* sx = Wih + n * 128 + k0;
      wfh[Q][c] = pack8(*(const float4*)sh, *(const float4*)(sh + 4));
      wfx[Q][c] = pack8(*(const float4*)sx, *(const float4*)(sx + 4));
    }
  }

  const int ur = (lane >> 4) & 1;
  const int uj = w * 16 + l15;
  float cst = 0.f;

  // staging thread mapping: 512 thr cover 16 rows x 128 cols (4 floats each)
  const int sm = tid >> 5;          // xs row 0..15  (tl = sm>>1, r = sm&1)
  const int sc = (tid & 31) * 4;    // col 0..124
  const int str = r0 + (sm & 1);
  const int stl = sm >> 1;

  // ---- prologue ----
  if (tid < 256) hx[0][tid >> 7][tid & 127] = 0;   // h(-1) = 0
  {  // stage xs[1] = x(block 0)
    const int tg = stl;
    const int tf = dir ? (511 - tg) : tg;
    const int word = words[str * 512 + tf];
    float4 av = *(const float4*)(emb + (size_t)word * 128 + sc);
    *(uint2*)&xs[1][sm][sc] = pack4(av);
  }
  WGBAR();
  // produce xp[0] from xs[1] (16 dense MFMAs/wave), bias in C-init
#pragma unroll
  for (int Q = 0; Q < 4; ++Q) {
    f32x4 pc = {biasP[Q], biasP[Q], biasP[Q], biasP[Q]};
#pragma unroll
    for (int c = 0; c < 4; ++c) {
      bf16x8 af = __builtin_bit_cast(bf16x8, *(const uint4*)&xs[1][l15][kq * 8 + c * 32]);
      pc = __builtin_amdgcn_mfma_f32_16x16x32_bf16(af, wfx[Q][c], pc, 0, 0, 0);
    }
#pragma unroll
    for (int rr = 0; rr < 4; ++rr)
      xp[0][kq * 4 + rr][w * 16 + l15][Q] = f2bf(pc[rr]);
  }
  {  // stage xs[0] = x(block 1)
    const int tg = 8 + stl;
    const int tf = dir ? (511 - tg) : tg;
    const int word = words[str * 512 + tf];
    float4 av = *(const float4*)(emb + (size_t)word * 128 + sc);
    *(uint2*)&xs[0][sm][sc] = pack4(av);
  }
  WGBAR();

  int sword = 0;
  float4 se0 = make_float4(0.f, 0.f, 0.f, 0.f);

#pragma unroll 1
  for (int i = 0; i < 64; ++i) {   // 64 blocks of 8 steps
    const int pcon = i & 1;        // consume xp[pcon]; production reads xs[pcon]
    const int ppro = pcon ^ 1;     // produce xp[ppro]; staging writes xs[ppro]
    f32x4 pc = {0.f, 0.f, 0.f, 0.f};
#pragma unroll
    for (int s = 0; s < 8; ++s) {
      const int t = i * 8 + s;
      const int p = t & 1;
      // xp consumption: one b64 read (Q0..Q3 packed), used after shuffles
      const uint2 xq = *(const uint2*)&xp[pcon][2 * s + ur][uj][0];
      // staging pipeline for x(block i+2): word @s0, emb @s2, LDS write @s6
      if (i < 62) {
        if (s == 0) {
          const int tg = (i + 2) * 8 + stl;
          const int tf = dir ? (511 - tg) : tg;
          sword = words[str * 512 + tf];
        }
        if (s == 2) se0 = *(const float4*)(emb + (size_t)sword * 128 + sc);
        if (s == 6) *(uint2*)&xs[ppro][sm][sc] = pack4(se0);
      }
      // ---- recurrence MFMAs: gates_h = h @ Whh^T (K=128) ----
      f32x4 a0 = {0.f, 0.f, 0.f, 0.f}, a1 = a0, a2 = a0, a3 = a0;
      const ushort_t* abase = &hx[p][l15 & 1][kq * 8];
#pragma unroll
      for (int c = 0; c < 4; ++c) {
        bf16x8 af = __builtin_bit_cast(bf16x8, *(const uint4*)(abase + c * 32));
        a0 = __builtin_amdgcn_mfma_f32_16x16x32_bf16(af, wfh[0][c], a0, 0, 0, 0);
        a1 = __builtin_amdgcn_mfma_f32_16x16x32_bf16(af, wfh[1][c], a1, 0, 0, 0);
        a2 = __builtin_amdgcn_mfma_f32_16x16x32_bf16(af, wfh[2][c], a2, 0, 0, 0);
        a3 = __builtin_amdgcn_mfma_f32_16x16x32_bf16(af, wfh[3][c], a3, 0, 0, 0);
      }
      // ---- production MFMAs for block i+1 (independent; fills bubbles) ----
      if (i < 63) {
        const int Q = s >> 1;
        if ((s & 1) == 0) {
          pc = f32x4{biasP[Q], biasP[Q], biasP[Q], biasP[Q]};
          bf16x8 af0 = __builtin_bit_cast(bf16x8, *(const uint4*)&xs[pcon][l15][kq * 8]);
          bf16x8 af1 = __builtin_bit_cast(bf16x8, *(const uint4*)&xs[pcon][l15][kq * 8 + 32]);
          pc = __builtin_amdgcn_mfma_f32_16x16x32_bf16(af0, wfx[Q][0], pc, 0, 0, 0);
          pc = __builtin_amdgcn_mfma_f32_16x16x32_bf16(af1, wfx[Q][1], pc, 0, 0, 0);
        } else {
          bf16x8 af2 = __builtin_bit_cast(bf16x8, *(const uint4*)&xs[pcon][l15][kq * 8 + 64]);
          bf16x8 af3 = __builtin_bit_cast(bf16x8, *(const uint4*)&xs[pcon][l15][kq * 8 + 96]);
          pc = __builtin_amdgcn_mfma_f32_16x16x32_bf16(af2, wfx[Q][2], pc, 0, 0, 0);
          pc = __builtin_amdgcn_mfma_f32_16x16x32_bf16(af3, wfx[Q][3], pc, 0, 0, 0);
#pragma unroll
          for (int rr = 0; rr < 4; ++rr)
            xp[ppro][kq * 4 + rr][w * 16 + l15][Q] = f2bf(pc[rr]);
        }
      }
      // ---- redistribute: lanes<16 own row-0 gates (a*[0]); lanes 16-31
      //      fetch row-1 gates (a*[1]) from lane l15 -> 4 shuffles only.
      float g0, g1, g2, g3;
      {
        const float s0 = __shfl(a0[1], l15, 64);
        const float s1 = __shfl(a1[1], l15, 64);
        const float s2 = __shfl(a2[1], l15, 64);
        const float s3 = __shfl(a3[1], l15, 64);
        g0 = (lane < 16) ? a0[0] : s0;
        g1 = (lane < 16) ? a1[0] : s1;
        g2 = (lane < 16) ? a2[0] : s2;
        g3 = (lane < 16) ? a3[0] : s3;
      }
      // add xp (bias already folded into xp at production)
      g0 += __builtin_bit_cast(float, xq.x << 16);
      g1 += __builtin_bit_cast(float, xq.x & 0xffff0000u);
      g2 += __builtin_bit_cast(float, xq.y << 16);
      g3 += __builtin_bit_cast(float, xq.y & 0xffff0000u);
      // activations (all lanes; only lanes<32 meaningful, stores guarded)
      const float si = sigm(g0), sf = sigm(g1), so = sigm(g3);
      const float tg = tanha(g2);
      cst = sf * cst + si * tg;
      const float h = so * tanha(cst);
      const ushort_t hb = f2bf(h);
      if (lane < 32) {
        hx[p ^ 1][ur][uj] = hb;
        const int tf = dir ? (511 - t) : t;
        hout[(tf * 256 + r0 + ur) * 128 + uj] = hb;  // stays in flight
      }
      WGBAR();
    }
  }
}

// ---------------------------------------------------------------------------
// K3: emis[t*256+b][48] = [h_f|h_b] @ Wout^T + bout  (fp32 out)
// ---------------------------------------------------------------------------
__global__ __launch_bounds__(256, 2) void k3_emis(
    const ushort_t* __restrict__ h_f, const ushort_t* __restrict__ h_b,
    const float* __restrict__ Wout, const float* __restrict__ bout,
    float* __restrict__ emis) {
  const int w = threadIdx.x >> 6;
  const int lane = threadIdx.x & 63;
  const int m31 = lane & 31;
  const int q = lane >> 5;
  const int Mbase = blockIdx.x * 128 + w * 32;

  bf16x8 bfr[2][16];
  float bo[2];
#pragma unroll
  for (int T = 0; T < 2; ++T) {
    const int n = T * 32 + m31;
    if (n < 48) {
      bo[T] = bout[n];
#pragma unroll
      for (int c = 0; c < 16; ++c) {
        const float* src = Wout + n * 256 + c * 16 + q * 8;
        bfr[T][c] = pack8(*(const float4*)src, *(const float4*)(src + 4));
      }
    } else {
      bo[T] = 0.f;
#pragma unroll
      for (int c = 0; c < 16; ++c) bfr[T][c] = zero8();
    }
  }
  f32x16 acc0{}, acc1{};
  const ushort_t* hrf = h_f + (long)(Mbase + m31) * 128;
  const ushort_t* hrb = h_b + (long)(Mbase + m31) * 128;
#pragma unroll
  for (int c = 0; c < 16; ++c) {
    const ushort_t* src = (c < 8) ? (hrf + c * 16 + q * 8) : (hrb + (c - 8) * 16 + q * 8);
    bf16x8 af = __builtin_bit_cast(bf16x8, *(const uint4*)src);
    acc0 = __builtin_amdgcn_mfma_f32_32x32x16_bf16(af, bfr[0][c], acc0, 0, 0, 0);
    acc1 = __builtin_amdgcn_mfma_f32_32x32x16_bf16(af, bfr[1][c], acc1, 0, 0, 0);
  }
#pragma unroll
  for (int T = 0; T < 2; ++T) {
    const int n = T * 32 + m31;
    if (n >= 48) continue;
    f32x16 A = T ? acc1 : acc0;
#pragma unroll
    for (int r = 0; r < 16; ++r) {
      const int row = (r & 3) + ((r >> 2) << 3) + (q << 2);
      emis[(long)(Mbase + row) * 48 + n] = A[r] + bo[T];
    }
  }
}

// ---------------------------------------------------------------------------
// K4 v7: CRF forward, 16 chains per wave via MFMA (LDS C->B transform kept
// from the passing v6), chain trimmed:
//  - E = 2^{em*L2E} from depth-3 prefetch (independent of renorm exponent)
//  - renorm folded into the bf16 pack as an fp32 exponent-bits subtract;
//    current-step e = exponent of row-0 (quad-0 C-reg) via one __shfl
//  - masked steps: predicated ds_writes keep old D-hat; no dold state;
//    epilogue reads d16 and adds the exact int S
// grid = 16 WGs x 64 thr (one wave per WG).
// ---------------------------------------------------------------------------
__global__ __launch_bounds__(64) void k4_den(
    const int* __restrict__ words, const float* __restrict__ emis,
    const float* __restrict__ trans, const float* __restrict__ st,
    const float* __restrict__ et, float* __restrict__ denom) {
  const int lane = threadIdx.x;
  const int r = lane & 15;       // chain within WG (C/B column)
  const int kq = lane >> 4;      // quad
  const int b = blockIdx.x * 16 + r;

  __shared__ __align__(16) ushort_t d16[16][72];   // [chain][tag j], 2,304 B

  // ---- A-frags: PA[mt][c]; A[m = mt*16 + r][k-elem e] = P[i][j],
  //      i = c*32 + kq*8 + e, j = mt*16 + r ----
  bf16x8 PA[3][2];
#pragma unroll
  for (int mt = 0; mt < 3; ++mt)
#pragma unroll
    for (int c = 0; c < 2; ++c) {
      const int j = mt * 16 + r;
      uint_t qv[4];
#pragma unroll
      for (int p = 0; p < 4; ++p) {
        const int i0 = c * 32 + kq * 8 + 2 * p;
        const float v0 = (i0 < 48) ? fexp2(trans[i0 * 48 + j] * L2E) : 0.f;
        const float v1 = (i0 + 1 < 48) ? fexp2(trans[(i0 + 1) * 48 + j] * L2E) : 0.f;
        qv[p] = (uint_t)f2bf(v0) | ((uint_t)f2bf(v1) << 16);
      }
      PA[mt][c] = __builtin_bit_cast(bf16x8, make_uint4(qv[0], qv[1], qv[2], qv[3]));
    }

  // ---- init: v = 2^{(st+em0)*L2E} in C-layout; normalize by e0; S = e0 ----
  float vi[3][4];
#pragma unroll
  for (int mt = 0; mt < 3; ++mt)
#pragma unroll
    for (int rr = 0; rr < 4; ++rr) {
      const int j = mt * 16 + kq * 4 + rr;
      vi[mt][rr] = fexp2((st[j] + emis[b * 48 + j]) * L2E);
    }
  int ei0 = ((__builtin_bit_cast(int, vi[0][0]) >> 23) & 255) - 127;
  int S = __shfl(ei0, r, 64);   // e of row 0 for chain r
#pragma unroll
  for (int mt = 0; mt < 3; ++mt) {
    uint2 pk = make_uint2(rnbf(vi[mt][0], S) | (rnbf(vi[mt][1], S) << 16),
                          rnbf(vi[mt][2], S) | (rnbf(vi[mt][3], S) << 16));
    *(uint2*)&d16[r][mt * 16 + kq * 4] = pk;
  }
  bf16x8 bd[2];
  bd[0] = __builtin_bit_cast(bf16x8, *(const uint4*)&d16[r][kq * 8]);
  {
    uint4 u1 = *(const uint4*)&d16[r][32 + (kq & 1) * 8];
    if (kq >= 2) u1 = make_uint4(0u, 0u, 0u, 0u);
    bd[1] = __builtin_bit_cast(bf16x8, u1);
  }

  // em/words prefetch (depth 3)
  float4 emA[3], emB[3], emC[3];
#pragma unroll
  for (int mt = 0; mt < 3; ++mt) {
    emA[mt] = *(const float4*)&emis[(1 * 256 + b) * 48 + mt * 16 + kq * 4];
    emB[mt] = *(const float4*)&emis[(2 * 256 + b) * 48 + mt * 16 + kq * 4];
    emC[mt] = *(const float4*)&emis[(3 * 256 + b) * 48 + mt * 16 + kq * 4];
  }
  int wvA = words[b * 512 + 1];
  int wvB = words[b * 512 + 2];
  int wvC = words[b * 512 + 3];

#pragma unroll 1
  for (int t = 1; t < 512; ++t) {
    // E for current t: depends only on prefetched em (off the d/e chain)
    float EF[3][4];
#pragma unroll
    for (int mt = 0; mt < 3; ++mt)
#pragma unroll
      for (int rr = 0; rr < 4; ++rr)
        EF[mt][rr] = fexp2((&emA[mt].x)[rr] * L2E);
    const bool msk = (wvA != 0);
    // rotate prefetch; issue t+3 loads (stay in flight)
    const int tn = min(511, t + 3);
#pragma unroll
    for (int mt = 0; mt < 3; ++mt) { emA[mt] = emB[mt]; emB[mt] = emC[mt]; }
#pragma unroll
    for (int mt = 0; mt < 3; ++mt)
      emC[mt] = *(const float4*)&emis[(tn * 256 + b) * 48 + mt * 16 + kq * 4];
    wvA = wvB; wvB = wvC; wvC = words[b * 512 + tn];

    // ---- 6 MFMAs: C[m=j][n=chain] over 3 m-tiles x 2 K-chunks ----
    f32x4 C0{}, C1{}, C2{};
    C0 = __builtin_amdgcn_mfma_f32_16x16x32_bf16(PA[0][0], bd[0], C0, 0, 0, 0);
    C1 = __builtin_amdgcn_mfma_f32_16x16x32_bf16(PA[1][0], bd[0], C1, 0, 0, 0);
    C2 = __builtin_amdgcn_mfma_f32_16x16x32_bf16(PA[2][0], bd[0], C2, 0, 0, 0);
    C0 = __builtin_amdgcn_mfma_f32_16x16x32_bf16(PA[0][1], bd[1], C0, 0, 0, 0);
    C1 = __builtin_amdgcn_mfma_f32_16x16x32_bf16(PA[1][1], bd[1], C1, 0, 0, 0);
    C2 = __builtin_amdgcn_mfma_f32_16x16x32_bf16(PA[2][1], bd[1], C2, 0, 0, 0);

    // ---- v = C * E; e = exponent of row 0 (quad-0 reg 0), one shuffle ----
    float v0[4], v1[4], v2[4];
#pragma unroll
    for (int rr = 0; rr < 4; ++rr) {
      v0[rr] = C0[rr] * EF[0][rr];
      v1[rr] = C1[rr] * EF[1][rr];
      v2[rr] = C2[rr] * EF[2][rr];
    }
    const int ei = ((__builtin_bit_cast(int, v0[0]) >> 23) & 255) - 127;
    const int e = __shfl(ei, r, 64);

    // ---- pack with renorm (u - e<<23, RNE) ; predicated write (mask) ----
    if (msk) {
      uint2 p0 = make_uint2(rnbf(v0[0], e) | (rnbf(v0[1], e) << 16),
                            rnbf(v0[2], e) | (rnbf(v0[3], e) << 16));
      uint2 p1 = make_uint2(rnbf(v1[0], e) | (rnbf(v1[1], e) << 16),
                            rnbf(v1[2], e) | (rnbf(v1[3], e) << 16));
      uint2 p2 = make_uint2(rnbf(v2[0], e) | (rnbf(v2[1], e) << 16),
                            rnbf(v2[2], e) | (rnbf(v2[3], e) << 16));
      *(uint2*)&d16[r][0 + kq * 4] = p0;
      *(uint2*)&d16[r][16 + kq * 4] = p1;
      *(uint2*)&d16[r][32 + kq * 4] = p2;
      S += e;
    }
    // ---- re-read B-frags (DS in-order per wave; compiler inserts waits) ----
    bd[0] = __builtin_bit_cast(bf16x8, *(const uint4*)&d16[r][kq * 8]);
    {
      uint4 u1 = *(const uint4*)&d16[r][32 + (kq & 1) * 8];
      if (kq >= 2) u1 = make_uint4(0u, 0u, 0u, 0u);
      bd[1] = __builtin_bit_cast(bf16x8, u1);
    }
  }

  // ---- epilogue: denom = (S + log2(sum_j Dhat[j]*2^{et_j*L2E})) * ln2 ----
  float psum = 0.f;
#pragma unroll
  for (int mt = 0; mt < 3; ++mt) {
    uint2 pk = *(const uint2*)&d16[r][mt * 16 + kq * 4];
    const float d0 = __builtin_bit_cast(float, pk.x << 16);
    const float d1 = __builtin_bit_cast(float, pk.x & 0xffff0000u);
    const float d2 = __builtin_bit_cast(float, pk.y << 16);
    const float d3 = __builtin_bit_cast(float, pk.y & 0xffff0000u);
    const int j = mt * 16 + kq * 4;
    psum += d0 * fexp2(et[j] * L2E) + d1 * fexp2(et[j + 1] * L2E) +
            d2 * fexp2(et[j + 2] * L2E) + d3 * fexp2(et[j + 3] * L2E);
  }
  psum += __shfl_xor(psum, 16, 64);
  psum += __shfl_xor(psum, 32, 64);
  if (lane < 16) denom[b] = ((float)S + flog2(psum)) * LN2;
}

// ---------------------------------------------------------------------------
// K4b: CRF numerator (gold path score).
// ---------------------------------------------------------------------------
__global__ void k4b_num(const int* __restrict__ words, const int* __restrict__ tags,
                        const float* __restrict__ emis, const float* __restrict__ trans,
                        const float* __restrict__ st, const float* __restrict__ et,
                        float* __restrict__ num) {
  const int b = blockIdx.x;
  const int lane = threadIdx.x;
  float s = 0.f;
  int cnt = 0;
#pragma unroll 1
  for (int s8 = 0; s8 < 8; ++s8) {
    const int t = lane + (s8 << 6);
    const int wv = words[b * 512 + t];
    const int tg = tags[b * 512 + t];
    const bool mt = (wv != 0);
    cnt += mt ? 1 : 0;
    if (t == 0) {
      s += st[tg] + emis[b * 48 + tg];
    } else if (mt) {
      const int tp = tags[b * 512 + t - 1];
      s += trans[tp * 48 + tg] + emis[(t * 256 + b) * 48 + tg];
    }
  }
#pragma unroll
  for (int d = 32; d; d >>= 1) {
    s += __shfl_xor(s, d, 64);
    cnt += __shfl_xor(cnt, d, 64);
  }
  if (lane == 0) {
    const int lt = tags[b * 512 + cnt - 1];
    num[b] = s + et[lt];
  }
}

// ---------------------------------------------------------------------------
// K5: loss = -mean(num - denom)
// ---------------------------------------------------------------------------
__global__ void k5_loss(const float* __restrict__ num, const float* __restrict__ denom,
                        float* __restrict__ out) {
  const int tid = threadIdx.x;
  float v = num[tid] - denom[tid];
#pragma unroll
  for (int d = 32; d; d >>= 1) v += __shfl_xor(v, d, 64);
  __shared__ float p[4];
  if ((tid & 63) == 0) p[tid >> 6] = v;
  __syncthreads();
  if (tid == 0) out[0] = -(p[0] + p[1] + p[2] + p[3]) * (1.0f / 256.0f);
}

// ---------------------------------------------------------------------------
extern "C" void kernel_launch(void* const* d_in, const int* in_sizes, int n_in,
                              void* d_out, int out_size, void* d_ws, size_t ws_size,
                              hipStream_t stream) {
  (void)in_sizes; (void)n_in; (void)out_size; (void)ws_size;
  const int*   words = (const int*)d_in[0];
  const int*   tags  = (const int*)d_in[1];
  // d_in[2] = mask (bool) -- unused; reconstructed as words != 0
  const float* emb   = (const float*)d_in[3];
  const float* Wih_f = (const float*)d_in[4];
  const float* Whh_f = (const float*)d_in[5];
  const float* bih_f = (const float*)d_in[6];
  const float* bhh_f = (const float*)d_in[7];
  const float* Wih_b = (const float*)d_in[8];
  const float* Whh_b = (const float*)d_in[9];
  const float* bih_b = (const float*)d_in[10];
  const float* bhh_b = (const float*)d_in[11];
  const float* Wout  = (const float*)d_in[12];
  const float* bout  = (const float*)d_in[13];
  const float* trans = (const float*)d_in[14];
  const float* st    = (const float*)d_in[15];
  const float* et    = (const float*)d_in[16];

  char* ws = (char*)d_ws;
  ushort_t* h_f   = (ushort_t*)(ws);                    // 33,554,432 B
  ushort_t* h_b   = (ushort_t*)(ws + 33554432);         // 33,554,432 B
  float*    emis  = (float*)   (ws + 67108864);         // 25,165,824 B
  float*    denom = (float*)   (ws + 92274688);         //      1,024 B
  float*    num   = (float*)   (ws + 92275712);         //      1,024 B
  // total ws needed: ~92.3 MB (within the known-good 125.8 MB envelope)

  k2_lstm <<<256, 512, 0, stream>>>(words, emb,
                                    Wih_f, Whh_f, bih_f, bhh_f,
                                    Wih_b, Whh_b, bih_b, bhh_b,
                                    h_f, h_b);
  k3_emis <<<1024, 256, 0, stream>>>(h_f, h_b, Wout, bout, emis);
  k4_den  <<<16, 64, 0, stream>>>(words, emis, trans, st, et, denom);
  k4b_num <<<256, 64, 0, stream>>>(words, tags, emis, trans, st, et, num);
  k5_loss <<<1, 256, 0, stream>>>(num, denom, (float*)d_out);
}